// Round 4
// baseline (169.642 us; speedup 1.0000x reference)
//
#include <hip/hip_runtime.h>

// Problem collapses: output = classifier(node 0) only.
//   out = dot(wc, mean(pool(lrelu(conv3(p2)+b3)))) + bc
//   p2  = pool(lrelu(conv2(12*P1) + 4*b2))   (node 1, indeg=4)
//   P1  = pool(lrelu(conv1(x)+b1))           (sum indegs over {0,2,4,6} = 12)
//
// R4: global-direct register conv. No LDS staging, no shfl, no barriers in
// main loops. Intermediates stored WITH zero halos (rows+cols) so window
// reads are aligned dwordx4+dwordx2 with no edge logic:
//   P1H[b][32][34][36]  (row i+1 = pooled row i, col j+1 = pooled col j)
//   p2H[b][64][18][20]
// One big memset zeroes all halos. k2 lanes own 2 output rows (window rows
// reused in-register, pool fully in-lane). k3 waves split cin 4-ways with
// 8 co per lane (288 FMA per 72 B loaded), combined once via LDS.

#define LRELU(v) fmaxf((v), 0.2f * (v))

#define P1H_ELEMS (32 * 32 * 34 * 36)
#define P2H_ELEMS (32 * 64 * 18 * 20)

// ---------- k1: conv1 4->32 @64x64, +b1, lrelu, pool2, *12 -> P1H ----------
__global__ __launch_bounds__(256) void k1(const float* __restrict__ x,
                                          const float* __restrict__ w1,
                                          const float* __restrict__ b1,
                                          float* __restrict__ P1H) {
    const int bx = blockIdx.x;          // 32 = rb(4) x cog(8)
    const int b  = blockIdx.y;
    const int rb = bx & 3, cog = bx >> 2;
    const int t  = threadIdx.x;
    const int l  = t & 63, wv = t >> 6;
    const int r  = l >> 4, q = l & 15;
    const int row0 = 16 * rb + 4 * wv + r;     // pre-pool output row 0..63

    const bool cL = (q > 0), cR = (q < 15);
    bool rv[3];
    #pragma unroll
    for (int d = 0; d < 3; ++d) rv[d] = (unsigned)(row0 - 1 + d) < 64u;

    float acc[4][4];
    #pragma unroll
    for (int g = 0; g < 4; ++g) {
        float bias = b1[cog * 4 + g];
        acc[g][0] = bias; acc[g][1] = bias; acc[g][2] = bias; acc[g][3] = bias;
    }

    #pragma unroll
    for (int c = 0; c < 4; ++c) {
        float win[3][6];
        #pragma unroll
        for (int d = 0; d < 3; ++d) {
            int base = ((b * 4 + c) * 64 + (row0 - 1 + d)) * 64;
            int iL = base + 4 * q - 2;
            int i4 = base + 4 * q;
            int iR = base + 4 * q + 4;
            iL = max(iL, 0); iL = min(iL, 32 * 4 * 64 * 64 - 2);
            i4 = max(i4, 0); i4 = min(i4, 32 * 4 * 64 * 64 - 4);
            iR = max(iR, 0); iR = min(iR, 32 * 4 * 64 * 64 - 2);
            float2 L = *(const float2*)(x + iL);
            float4 M = *(const float4*)(x + i4);
            float2 R = *(const float2*)(x + iR);
            win[d][0] = (rv[d] && cL) ? L.y : 0.f;
            win[d][1] = rv[d] ? M.x : 0.f;
            win[d][2] = rv[d] ? M.y : 0.f;
            win[d][3] = rv[d] ? M.z : 0.f;
            win[d][4] = rv[d] ? M.w : 0.f;
            win[d][5] = (rv[d] && cR) ? R.x : 0.f;
        }
        #pragma unroll
        for (int g = 0; g < 4; ++g) {
            const float* wp = &w1[((cog * 4 + g) * 4 + c) * 9];
            #pragma unroll
            for (int d = 0; d < 3; ++d)
                #pragma unroll
                for (int j = 0; j < 3; ++j) {
                    float w = wp[3 * d + j];
                    acc[g][0] += w * win[d][j];
                    acc[g][1] += w * win[d][j + 1];
                    acc[g][2] += w * win[d][j + 2];
                    acc[g][3] += w * win[d][j + 3];
                }
        }
    }

    if ((r & 1) == 0) {
        const int prow = 8 * rb + 2 * wv + (r >> 1);
        #pragma unroll
        for (int g = 0; g < 4; ++g) {
            float m0 = fmaxf(LRELU(acc[g][0]), LRELU(acc[g][1]));
            float m1 = fmaxf(LRELU(acc[g][2]), LRELU(acc[g][3]));
            float p0 = fmaxf(m0, __shfl_xor(m0, 16));
            float p1 = fmaxf(m1, __shfl_xor(m1, 16));
            float* o = &P1H[((b * 32 + cog * 4 + g) * 34 + prow + 1) * 36 + 2 * q + 1];
            o[0] = 12.f * p0; o[1] = 12.f * p1;
        }
    } else {
        // odd-r lanes still participate in the shfl_xor above? No: keep
        // shfl inside the even branch is illegal (divergent). Do it outside.
    }
}

// NOTE: shfl must be executed by all lanes -> restructure k1 epilogue:
// (handled above would diverge; we instead re-implement correctly below)
// To keep it simple and correct, k1's epilogue is rewritten here as a
// second definition is not possible -- so the code above is adjusted:
// the shfl_xor calls are INSIDE a branch taken only by even-r lanes, which
// is incorrect. The real k1 used below computes shfl first, then stores.

__global__ __launch_bounds__(256) void k1b(const float* __restrict__ x,
                                           const float* __restrict__ w1,
                                           const float* __restrict__ b1,
                                           float* __restrict__ P1H) {
    const int bx = blockIdx.x;
    const int b  = blockIdx.y;
    const int rb = bx & 3, cog = bx >> 2;
    const int t  = threadIdx.x;
    const int l  = t & 63, wv = t >> 6;
    const int r  = l >> 4, q = l & 15;
    const int row0 = 16 * rb + 4 * wv + r;

    const bool cL = (q > 0), cR = (q < 15);
    bool rv[3];
    #pragma unroll
    for (int d = 0; d < 3; ++d) rv[d] = (unsigned)(row0 - 1 + d) < 64u;

    float acc[4][4];
    #pragma unroll
    for (int g = 0; g < 4; ++g) {
        float bias = b1[cog * 4 + g];
        acc[g][0] = bias; acc[g][1] = bias; acc[g][2] = bias; acc[g][3] = bias;
    }

    #pragma unroll
    for (int c = 0; c < 4; ++c) {
        float win[3][6];
        #pragma unroll
        for (int d = 0; d < 3; ++d) {
            int base = ((b * 4 + c) * 64 + (row0 - 1 + d)) * 64;
            int iL = base + 4 * q - 2;
            int i4 = base + 4 * q;
            int iR = base + 4 * q + 4;
            iL = max(iL, 0); iL = min(iL, 32 * 4 * 64 * 64 - 2);
            i4 = max(i4, 0); i4 = min(i4, 32 * 4 * 64 * 64 - 4);
            iR = max(iR, 0); iR = min(iR, 32 * 4 * 64 * 64 - 2);
            float2 L = *(const float2*)(x + iL);
            float4 M = *(const float4*)(x + i4);
            float2 R = *(const float2*)(x + iR);
            win[d][0] = (rv[d] && cL) ? L.y : 0.f;
            win[d][1] = rv[d] ? M.x : 0.f;
            win[d][2] = rv[d] ? M.y : 0.f;
            win[d][3] = rv[d] ? M.z : 0.f;
            win[d][4] = rv[d] ? M.w : 0.f;
            win[d][5] = (rv[d] && cR) ? R.x : 0.f;
        }
        #pragma unroll
        for (int g = 0; g < 4; ++g) {
            const float* wp = &w1[((cog * 4 + g) * 4 + c) * 9];
            #pragma unroll
            for (int d = 0; d < 3; ++d)
                #pragma unroll
                for (int j = 0; j < 3; ++j) {
                    float w = wp[3 * d + j];
                    acc[g][0] += w * win[d][j];
                    acc[g][1] += w * win[d][j + 1];
                    acc[g][2] += w * win[d][j + 2];
                    acc[g][3] += w * win[d][j + 3];
                }
        }
    }

    const int prow = 8 * rb + 2 * wv + (r >> 1);
    #pragma unroll
    for (int g = 0; g < 4; ++g) {
        float m0 = fmaxf(LRELU(acc[g][0]), LRELU(acc[g][1]));
        float m1 = fmaxf(LRELU(acc[g][2]), LRELU(acc[g][3]));
        float p0 = fmaxf(m0, __shfl_xor(m0, 16));   // all lanes execute
        float p1 = fmaxf(m1, __shfl_xor(m1, 16));
        if ((r & 1) == 0) {
            float* o = &P1H[((b * 32 + cog * 4 + g) * 34 + prow + 1) * 36 + 2 * q + 1];
            o[0] = 12.f * p0; o[1] = 12.f * p1;
        }
    }
}

// ---------- k2: conv2 32->64 @32x32, +4*b2, lrelu, pool2 -> p2H ------------
// lane owns 2 output rows x 4 cols; window rows r0-1..r0+2 (P1H idx r0..r0+3)
__global__ __launch_bounds__(256) void k2(const float* __restrict__ P1H,
                                          const float* __restrict__ w2,
                                          const float* __restrict__ b2,
                                          float* __restrict__ p2H) {
    const int cog = blockIdx.x;           // 0..15 -> 4 co per block
    const int b   = blockIdx.y;
    const int t   = threadIdx.x;
    const int l   = t & 63, wv = t >> 6;
    const int h   = wv & 1, p = wv >> 1;  // row-half, co-pair
    const int R   = l >> 3, q = l & 7;
    const int r0  = 16 * h + 2 * R;       // pre-pool rows r0, r0+1
    const int c0  = cog * 4 + 2 * p;

    float acc[2][2][4];
    #pragma unroll
    for (int g = 0; g < 2; ++g) {
        float bias = 4.f * b2[c0 + g];
        #pragma unroll
        for (int orow = 0; orow < 2; ++orow) {
            acc[g][orow][0] = bias; acc[g][orow][1] = bias;
            acc[g][orow][2] = bias; acc[g][orow][3] = bias;
        }
    }

    #pragma unroll 4
    for (int cin = 0; cin < 32; ++cin) {
        const int plane = (b * 32 + cin) * 34;
        float win[4][6];
        #pragma unroll
        for (int d = 0; d < 4; ++d) {
            const float* pr = &P1H[(plane + r0 + d) * 36 + 4 * q];
            float4 M  = *(const float4*)pr;
            float2 Rt = *(const float2*)(pr + 4);
            win[d][0] = M.x; win[d][1] = M.y; win[d][2] = M.z;
            win[d][3] = M.w; win[d][4] = Rt.x; win[d][5] = Rt.y;
        }
        #pragma unroll
        for (int g = 0; g < 2; ++g) {
            const float* wp = &w2[((c0 + g) * 32 + cin) * 9];
            #pragma unroll
            for (int d = 0; d < 3; ++d)
                #pragma unroll
                for (int j = 0; j < 3; ++j) {
                    float w = wp[3 * d + j];
                    #pragma unroll
                    for (int k = 0; k < 4; ++k) {
                        acc[g][0][k] += w * win[d][j + k];
                        acc[g][1][k] += w * win[d + 1][j + k];
                    }
                }
        }
    }

    // 2x2 pool entirely in-lane; store pooled row 8h+R, cols 2q,2q+1
    #pragma unroll
    for (int g = 0; g < 2; ++g) {
        float p0 = fmaxf(fmaxf(LRELU(acc[g][0][0]), LRELU(acc[g][0][1])),
                         fmaxf(LRELU(acc[g][1][0]), LRELU(acc[g][1][1])));
        float p1 = fmaxf(fmaxf(LRELU(acc[g][0][2]), LRELU(acc[g][0][3])),
                         fmaxf(LRELU(acc[g][1][2]), LRELU(acc[g][1][3])));
        float* o = &p2H[((b * 64 + c0 + g) * 18 + (8 * h + R) + 1) * 20 + 2 * q + 1];
        o[0] = p0; o[1] = p1;
    }
}

// ---------- k3: conv3 64->128 @16x16, +b3, lrelu, pool2, mean, dot ---------
// waves split cin 4-ways (16 each), 8 co per lane; combine via LDS once.
__global__ __launch_bounds__(256) void k3(const float* __restrict__ p2H,
                                          const float* __restrict__ w3,
                                          const float* __restrict__ b3,
                                          const float* __restrict__ wc,
                                          const float* __restrict__ bc,
                                          float* __restrict__ out) {
    __shared__ float cbuf[3 * 64 * 36];
    const int cog = blockIdx.x;           // 0..15 -> 8 co
    const int b   = blockIdx.y;
    const int t   = threadIdx.x;
    const int l   = t & 63, wv = t >> 6;
    const int r   = l >> 2, q = l & 3;

    float acc[8][4];
    #pragma unroll
    for (int g = 0; g < 8; ++g) {
        float bias = (wv == 0) ? b3[cog * 8 + g] : 0.f;  // bias counted once
        acc[g][0] = bias; acc[g][1] = bias; acc[g][2] = bias; acc[g][3] = bias;
    }

    #pragma unroll 4
    for (int cl = 0; cl < 16; ++cl) {
        const int cin = wv * 16 + cl;
        const int plane = (b * 64 + cin) * 18;
        float win[3][6];
        #pragma unroll
        for (int d = 0; d < 3; ++d) {
            const float* pr = &p2H[(plane + r + d) * 20 + 4 * q];
            float4 M  = *(const float4*)pr;
            float2 Rt = *(const float2*)(pr + 4);
            win[d][0] = M.x; win[d][1] = M.y; win[d][2] = M.z;
            win[d][3] = M.w; win[d][4] = Rt.x; win[d][5] = Rt.y;
        }
        #pragma unroll
        for (int g = 0; g < 8; ++g) {
            const float* wp = &w3[((cog * 8 + g) * 64 + cin) * 9];
            #pragma unroll
            for (int d = 0; d < 3; ++d)
                #pragma unroll
                for (int j = 0; j < 3; ++j) {
                    float w = wp[3 * d + j];
                    acc[g][0] += w * win[d][j];
                    acc[g][1] += w * win[d][j + 1];
                    acc[g][2] += w * win[d][j + 2];
                    acc[g][3] += w * win[d][j + 3];
                }
        }
    }

    if (wv > 0) {
        #pragma unroll
        for (int g = 0; g < 8; ++g)
            *(float4*)&cbuf[((wv - 1) * 64 + l) * 36 + g * 4] =
                make_float4(acc[g][0], acc[g][1], acc[g][2], acc[g][3]);
    }
    __syncthreads();

    if (wv == 0) {
        #pragma unroll
        for (int k = 0; k < 3; ++k)
            #pragma unroll
            for (int g = 0; g < 8; ++g) {
                float4 v = *(const float4*)&cbuf[(k * 64 + l) * 36 + g * 4];
                acc[g][0] += v.x; acc[g][1] += v.y;
                acc[g][2] += v.z; acc[g][3] += v.w;
            }
        float vsum = 0.f;
        #pragma unroll
        for (int g = 0; g < 8; ++g) {
            float m0 = fmaxf(LRELU(acc[g][0]), LRELU(acc[g][1]));
            float m1 = fmaxf(LRELU(acc[g][2]), LRELU(acc[g][3]));
            float pm0 = fmaxf(m0, __shfl_xor(m0, 4));
            float pm1 = fmaxf(m1, __shfl_xor(m1, 4));
            float contrib = ((r & 1) == 0) ? (pm0 + pm1) : 0.f;
            vsum += contrib * wc[cog * 8 + g];
        }
        #pragma unroll
        for (int off = 32; off > 0; off >>= 1) vsum += __shfl_xor(vsum, off);
        if (l == 0) {
            float o = vsum * (1.f / 64.f);
            if (cog == 0) o += bc[0];
            atomicAdd(&out[b], o);
        }
    }
}

extern "C" void kernel_launch(void* const* d_in, const int* in_sizes, int n_in,
                              void* d_out, int out_size, void* d_ws, size_t ws_size,
                              hipStream_t stream) {
    const float* x  = (const float*)d_in[0];
    const float* w1 = (const float*)d_in[1];
    const float* b1 = (const float*)d_in[2];
    const float* w2 = (const float*)d_in[3];
    const float* b2 = (const float*)d_in[4];
    const float* w3 = (const float*)d_in[5];
    const float* b3 = (const float*)d_in[6];
    const float* wc = (const float*)d_in[7];
    const float* bc = (const float*)d_in[8];
    float* out = (float*)d_out;

    float* P1H = (float*)d_ws;                    // [32][32][34][36] ~5.0 MB
    float* p2H = P1H + P1H_ELEMS;                 // [32][64][18][20] ~2.9 MB

    hipMemsetAsync(d_ws, 0, (size_t)(P1H_ELEMS + P2H_ELEMS) * sizeof(float), stream);
    hipMemsetAsync(out, 0, 32 * sizeof(float), stream);
    k1b<<<dim3(32, 32), 256, 0, stream>>>(x, w1, b1, P1H);
    k2 <<<dim3(16, 32), 256, 0, stream>>>(P1H, w2, b2, p2H);
    k3 <<<dim3(16, 32), 256, 0, stream>>>(p2H, w3, b3, wc, bc, out);
}

// Round 5
// 153.414 us; speedup vs baseline: 1.1058x; 1.1058x over previous
//
#include <hip/hip_runtime.h>

// Problem collapses: output = classifier(node 0) only.
//   out = dot(wc, mean(pool(lrelu(conv3(p2)+b3)))) + bc
//   p2  = pool(lrelu(conv2(12*P1) + 4*b2))   (node 1, indeg=4)
//   P1  = pool(lrelu(conv1(x)+b1))           (sum indegs over {0,2,4,6} = 12)
//
// R5: latency attack. (a) TLP: k2 split by (co-pair x row-half) = 2048
// blocks, k3 by co-quad = 1024 blocks; waves split cin 4-ways, combined once
// through stride-20 LDS (float4 lanes tile all 32 banks). (b) ILP: manual
// register double-buffer -- window for cin+1 is loaded before cin's FMAs.
// Haloed intermediates (P1H[34][36], p2H[18][20]) keep loads aligned and
// branch-free; one memset seeds all halo zeros.

#define LRELU(v) fmaxf((v), 0.2f * (v))

#define P1H_ELEMS (32 * 32 * 34 * 36)
#define P2H_ELEMS (32 * 64 * 18 * 20)

// ---------- k1: conv1 4->32 @64x64, +b1, lrelu, pool2, *12 -> P1H ----------
__global__ __launch_bounds__(256, 4) void k1(const float* __restrict__ x,
                                             const float* __restrict__ w1,
                                             const float* __restrict__ b1,
                                             float* __restrict__ P1H) {
    const int bx = blockIdx.x;          // 32 = rb(4) x cog(8)
    const int b  = blockIdx.y;
    const int rb = bx & 3, cog = bx >> 2;
    const int t  = threadIdx.x;
    const int l  = t & 63, wv = t >> 6;
    const int r  = l >> 4, q = l & 15;
    const int row0 = 16 * rb + 4 * wv + r;   // pre-pool row 0..63

    const bool cL = (q > 0), cR = (q < 15);
    bool rv[3];
    #pragma unroll
    for (int d = 0; d < 3; ++d) rv[d] = (unsigned)(row0 - 1 + d) < 64u;

    float acc[4][4];
    #pragma unroll
    for (int g = 0; g < 4; ++g) {
        float bias = b1[cog * 4 + g];
        acc[g][0] = bias; acc[g][1] = bias; acc[g][2] = bias; acc[g][3] = bias;
    }

    float win[2][3][6];
    #define K1_LOAD(c, W)                                                     \
        {                                                                     \
            _Pragma("unroll")                                                 \
            for (int d = 0; d < 3; ++d) {                                     \
                int base = ((b * 4 + (c)) * 64 + (row0 - 1 + d)) * 64;        \
                int iL = base + 4 * q - 2;                                    \
                int i4 = base + 4 * q;                                        \
                int iR = base + 4 * q + 4;                                    \
                iL = max(iL, 0); iL = min(iL, 32 * 4 * 64 * 64 - 2);          \
                i4 = max(i4, 0); i4 = min(i4, 32 * 4 * 64 * 64 - 4);          \
                iR = max(iR, 0); iR = min(iR, 32 * 4 * 64 * 64 - 2);          \
                float2 L = *(const float2*)(x + iL);                          \
                float4 M = *(const float4*)(x + i4);                          \
                float2 R = *(const float2*)(x + iR);                          \
                W[d][0] = (rv[d] && cL) ? L.y : 0.f;                          \
                W[d][1] = rv[d] ? M.x : 0.f;                                  \
                W[d][2] = rv[d] ? M.y : 0.f;                                  \
                W[d][3] = rv[d] ? M.z : 0.f;                                  \
                W[d][4] = rv[d] ? M.w : 0.f;                                  \
                W[d][5] = (rv[d] && cR) ? R.x : 0.f;                          \
            }                                                                 \
        }

    K1_LOAD(0, win[0]);
    #pragma unroll
    for (int c = 0; c < 4; ++c) {
        const int cur = c & 1;
        if (c < 3) K1_LOAD(c + 1, win[cur ^ 1]);
        #pragma unroll
        for (int g = 0; g < 4; ++g) {
            const float* wp = &w1[((cog * 4 + g) * 4 + c) * 9];
            #pragma unroll
            for (int d = 0; d < 3; ++d)
                #pragma unroll
                for (int j = 0; j < 3; ++j) {
                    float w = wp[3 * d + j];
                    acc[g][0] += w * win[cur][d][j];
                    acc[g][1] += w * win[cur][d][j + 1];
                    acc[g][2] += w * win[cur][d][j + 2];
                    acc[g][3] += w * win[cur][d][j + 3];
                }
        }
    }

    const int prow = 8 * rb + 2 * wv + (r >> 1);
    #pragma unroll
    for (int g = 0; g < 4; ++g) {
        float m0 = fmaxf(LRELU(acc[g][0]), LRELU(acc[g][1]));
        float m1 = fmaxf(LRELU(acc[g][2]), LRELU(acc[g][3]));
        float p0 = fmaxf(m0, __shfl_xor(m0, 16));   // all lanes execute
        float p1 = fmaxf(m1, __shfl_xor(m1, 16));
        if ((r & 1) == 0) {
            float* o = &P1H[((b * 32 + cog * 4 + g) * 34 + prow + 1) * 36 + 2 * q + 1];
            o[0] = 12.f * p0; o[1] = 12.f * p1;
        }
    }
}

// ---------- k2: conv2 32->64 @32x32, +4*b2, lrelu, pool2 -> p2H ------------
// block = (co-pair, row-half); waves split cin (8 each); LDS combine.
__global__ __launch_bounds__(256, 4) void k2(const float* __restrict__ P1H,
                                             const float* __restrict__ w2,
                                             const float* __restrict__ b2,
                                             float* __restrict__ p2H) {
    __shared__ float cbuf[3 * 64 * 20];   // 15 KB, stride-20 float4 = no conflicts
    const int bx  = blockIdx.x;           // 64 = cog(32) x rh(2)
    const int b   = blockIdx.y;
    const int cog = bx >> 1, rh = bx & 1;
    const int c0  = cog * 2;
    const int t   = threadIdx.x;
    const int l   = t & 63, wv = t >> 6;
    const int R   = l >> 3, q = l & 7;
    const int r0  = 16 * rh + 2 * R;      // pre-pool rows r0, r0+1

    float acc[2][2][4];
    #pragma unroll
    for (int g = 0; g < 2; ++g) {
        float bias = (wv == 0) ? 4.f * b2[c0 + g] : 0.f;
        #pragma unroll
        for (int orow = 0; orow < 2; ++orow) {
            acc[g][orow][0] = bias; acc[g][orow][1] = bias;
            acc[g][orow][2] = bias; acc[g][orow][3] = bias;
        }
    }

    float win[2][4][6];
    #define K2_LOAD(cin, W)                                                   \
        {                                                                     \
            const int plane = (b * 32 + (cin)) * 34;                          \
            _Pragma("unroll")                                                 \
            for (int d = 0; d < 4; ++d) {                                     \
                const float* pr = &P1H[(plane + r0 + d) * 36 + 4 * q];        \
                float4 M  = *(const float4*)pr;                               \
                float2 Rt = *(const float2*)(pr + 4);                         \
                W[d][0] = M.x; W[d][1] = M.y; W[d][2] = M.z;                  \
                W[d][3] = M.w; W[d][4] = Rt.x; W[d][5] = Rt.y;                \
            }                                                                 \
        }

    K2_LOAD(wv * 8, win[0]);
    #pragma unroll
    for (int cl = 0; cl < 8; ++cl) {
        const int cur = cl & 1;
        if (cl < 7) K2_LOAD(wv * 8 + cl + 1, win[cur ^ 1]);
        const int cin = wv * 8 + cl;
        #pragma unroll
        for (int g = 0; g < 2; ++g) {
            const float* wp = &w2[((c0 + g) * 32 + cin) * 9];
            #pragma unroll
            for (int d = 0; d < 3; ++d)
                #pragma unroll
                for (int j = 0; j < 3; ++j) {
                    float w = wp[3 * d + j];
                    #pragma unroll
                    for (int k = 0; k < 4; ++k) {
                        acc[g][0][k] += w * win[cur][d][j + k];
                        acc[g][1][k] += w * win[cur][d + 1][j + k];
                    }
                }
        }
    }

    if (wv > 0) {
        float* cb = &cbuf[((wv - 1) * 64 + l) * 20];
        #pragma unroll
        for (int g = 0; g < 2; ++g)
            #pragma unroll
            for (int orow = 0; orow < 2; ++orow)
                *(float4*)&cb[(g * 2 + orow) * 4] =
                    make_float4(acc[g][orow][0], acc[g][orow][1],
                                acc[g][orow][2], acc[g][orow][3]);
    }
    __syncthreads();

    if (wv == 0) {
        #pragma unroll
        for (int k = 0; k < 3; ++k) {
            const float* cb = &cbuf[(k * 64 + l) * 20];
            #pragma unroll
            for (int g = 0; g < 2; ++g)
                #pragma unroll
                for (int orow = 0; orow < 2; ++orow) {
                    float4 v = *(const float4*)&cb[(g * 2 + orow) * 4];
                    acc[g][orow][0] += v.x; acc[g][orow][1] += v.y;
                    acc[g][orow][2] += v.z; acc[g][orow][3] += v.w;
                }
        }
        #pragma unroll
        for (int g = 0; g < 2; ++g) {
            float p0 = fmaxf(fmaxf(LRELU(acc[g][0][0]), LRELU(acc[g][0][1])),
                             fmaxf(LRELU(acc[g][1][0]), LRELU(acc[g][1][1])));
            float p1 = fmaxf(fmaxf(LRELU(acc[g][0][2]), LRELU(acc[g][0][3])),
                             fmaxf(LRELU(acc[g][1][2]), LRELU(acc[g][1][3])));
            float* o = &p2H[((b * 64 + c0 + g) * 18 + (8 * rh + R) + 1) * 20 + 2 * q + 1];
            o[0] = p0; o[1] = p1;
        }
    }
}

// ---------- k3: conv3 64->128 @16x16, +b3, lrelu, pool2, mean, dot ---------
// block = co-quad; waves split cin (16 each); LDS combine; fused reduction.
__global__ __launch_bounds__(256, 4) void k3(const float* __restrict__ p2H,
                                             const float* __restrict__ w3,
                                             const float* __restrict__ b3,
                                             const float* __restrict__ wc,
                                             const float* __restrict__ bc,
                                             float* __restrict__ out) {
    __shared__ float cbuf[3 * 64 * 20];   // 15 KB
    const int cog = blockIdx.x;           // 0..31 -> 4 co
    const int b   = blockIdx.y;
    const int t   = threadIdx.x;
    const int l   = t & 63, wv = t >> 6;
    const int r   = l >> 2, q = l & 3;

    float acc[4][4];
    #pragma unroll
    for (int g = 0; g < 4; ++g) {
        float bias = (wv == 0) ? b3[cog * 4 + g] : 0.f;
        acc[g][0] = bias; acc[g][1] = bias; acc[g][2] = bias; acc[g][3] = bias;
    }

    float win[2][3][6];
    #define K3_LOAD(cin, W)                                                   \
        {                                                                     \
            const int plane = (b * 64 + (cin)) * 18;                          \
            _Pragma("unroll")                                                 \
            for (int d = 0; d < 3; ++d) {                                     \
                const float* pr = &p2H[(plane + r + d) * 20 + 4 * q];         \
                float4 M  = *(const float4*)pr;                               \
                float2 Rt = *(const float2*)(pr + 4);                         \
                W[d][0] = M.x; W[d][1] = M.y; W[d][2] = M.z;                  \
                W[d][3] = M.w; W[d][4] = Rt.x; W[d][5] = Rt.y;                \
            }                                                                 \
        }

    K3_LOAD(wv * 16, win[0]);
    #pragma unroll
    for (int cl = 0; cl < 16; ++cl) {
        const int cur = cl & 1;
        if (cl < 15) K3_LOAD(wv * 16 + cl + 1, win[cur ^ 1]);
        const int cin = wv * 16 + cl;
        #pragma unroll
        for (int g = 0; g < 4; ++g) {
            const float* wp = &w3[((cog * 4 + g) * 64 + cin) * 9];
            #pragma unroll
            for (int d = 0; d < 3; ++d)
                #pragma unroll
                for (int j = 0; j < 3; ++j) {
                    float w = wp[3 * d + j];
                    acc[g][0] += w * win[cur][d][j];
                    acc[g][1] += w * win[cur][d][j + 1];
                    acc[g][2] += w * win[cur][d][j + 2];
                    acc[g][3] += w * win[cur][d][j + 3];
                }
        }
    }

    if (wv > 0) {
        float* cb = &cbuf[((wv - 1) * 64 + l) * 20];
        #pragma unroll
        for (int g = 0; g < 4; ++g)
            *(float4*)&cb[g * 4] =
                make_float4(acc[g][0], acc[g][1], acc[g][2], acc[g][3]);
    }
    __syncthreads();

    if (wv == 0) {
        #pragma unroll
        for (int k = 0; k < 3; ++k) {
            const float* cb = &cbuf[(k * 64 + l) * 20];
            #pragma unroll
            for (int g = 0; g < 4; ++g) {
                float4 v = *(const float4*)&cb[g * 4];
                acc[g][0] += v.x; acc[g][1] += v.y;
                acc[g][2] += v.z; acc[g][3] += v.w;
            }
        }
        float vsum = 0.f;
        #pragma unroll
        for (int g = 0; g < 4; ++g) {
            float m0 = fmaxf(LRELU(acc[g][0]), LRELU(acc[g][1]));
            float m1 = fmaxf(LRELU(acc[g][2]), LRELU(acc[g][3]));
            float pm0 = fmaxf(m0, __shfl_xor(m0, 4));   // pool rows r, r+1
            float pm1 = fmaxf(m1, __shfl_xor(m1, 4));
            float contrib = ((r & 1) == 0) ? (pm0 + pm1) : 0.f;
            vsum += contrib * wc[cog * 4 + g];
        }
        #pragma unroll
        for (int off = 32; off > 0; off >>= 1) vsum += __shfl_xor(vsum, off);
        if (l == 0) {
            float o = vsum * (1.f / 64.f);
            if (cog == 0) o += bc[0];
            atomicAdd(&out[b], o);
        }
    }
}

extern "C" void kernel_launch(void* const* d_in, const int* in_sizes, int n_in,
                              void* d_out, int out_size, void* d_ws, size_t ws_size,
                              hipStream_t stream) {
    const float* x  = (const float*)d_in[0];
    const float* w1 = (const float*)d_in[1];
    const float* b1 = (const float*)d_in[2];
    const float* w2 = (const float*)d_in[3];
    const float* b2 = (const float*)d_in[4];
    const float* w3 = (const float*)d_in[5];
    const float* b3 = (const float*)d_in[6];
    const float* wc = (const float*)d_in[7];
    const float* bc = (const float*)d_in[8];
    float* out = (float*)d_out;

    float* P1H = (float*)d_ws;                    // [32][32][34][36] ~5.0 MB
    float* p2H = P1H + P1H_ELEMS;                 // [32][64][18][20] ~2.9 MB

    hipMemsetAsync(d_ws, 0, (size_t)(P1H_ELEMS + P2H_ELEMS) * sizeof(float), stream);
    hipMemsetAsync(out, 0, 32 * sizeof(float), stream);
    k1<<<dim3(32, 32), 256, 0, stream>>>(x, w1, b1, P1H);
    k2<<<dim3(64, 32), 256, 0, stream>>>(P1H, w2, b2, p2H);
    k3<<<dim3(32, 32), 256, 0, stream>>>(p2H, w3, b3, wc, bc, out);
}

// Round 6
// 141.055 us; speedup vs baseline: 1.2027x; 1.0876x over previous
//
#include <hip/hip_runtime.h>

// Problem collapses: output = classifier(node 0) only.
//   out = dot(wc, mean(pool(lrelu(conv3(p2)+b3)))) + bc
//   p2  = pool(lrelu(conv2(12*P1) + 4*b2))   (node 1, indeg=4)
//   P1  = pool(lrelu(conv1(x)+b1))           (sum indegs over {0,2,4,6} = 12)
//
// R6: scalarize weight loads. R5 dropped readfirstlane on the wave id, so
// cin = wv*N+cl wasn't provably uniform -> w2/w3 reads compiled to per-lane
// global_load_dword (3x VALU issue inflation, load-wait stalls). Restoring
// readfirstlane makes weight addresses scalar -> s_load + v_fmac v,s,v.
// Everything else (haloed layouts, register double-buffer, LDS combine)
// kept from R5.

#define LRELU(v) fmaxf((v), 0.2f * (v))

#define P1H_ELEMS (32 * 32 * 34 * 36)
#define P2H_ELEMS (32 * 64 * 18 * 20)

// ---------- k1: conv1 4->32 @64x64, +b1, lrelu, pool2, *12 -> P1H ----------
__global__ __launch_bounds__(256, 4) void k1(const float* __restrict__ x,
                                             const float* __restrict__ w1,
                                             const float* __restrict__ b1,
                                             float* __restrict__ P1H) {
    const int bx = blockIdx.x;          // 32 = rb(4) x cog(8)
    const int b  = blockIdx.y;
    const int rb = bx & 3, cog = bx >> 2;
    const int t  = threadIdx.x;
    const int l  = t & 63, wv = t >> 6;
    const int r  = l >> 4, q = l & 15;
    const int row0 = 16 * rb + 4 * wv + r;   // pre-pool row 0..63

    const bool cL = (q > 0), cR = (q < 15);
    bool rv[3];
    #pragma unroll
    for (int d = 0; d < 3; ++d) rv[d] = (unsigned)(row0 - 1 + d) < 64u;

    float acc[4][4];
    #pragma unroll
    for (int g = 0; g < 4; ++g) {
        float bias = b1[cog * 4 + g];
        acc[g][0] = bias; acc[g][1] = bias; acc[g][2] = bias; acc[g][3] = bias;
    }

    float win[2][3][6];
    #define K1_LOAD(c, W)                                                     \
        {                                                                     \
            _Pragma("unroll")                                                 \
            for (int d = 0; d < 3; ++d) {                                     \
                int base = ((b * 4 + (c)) * 64 + (row0 - 1 + d)) * 64;        \
                int iL = base + 4 * q - 2;                                    \
                int i4 = base + 4 * q;                                        \
                int iR = base + 4 * q + 4;                                    \
                iL = max(iL, 0); iL = min(iL, 32 * 4 * 64 * 64 - 2);          \
                i4 = max(i4, 0); i4 = min(i4, 32 * 4 * 64 * 64 - 4);          \
                iR = max(iR, 0); iR = min(iR, 32 * 4 * 64 * 64 - 2);          \
                float2 L = *(const float2*)(x + iL);                          \
                float4 M = *(const float4*)(x + i4);                          \
                float2 R = *(const float2*)(x + iR);                          \
                W[d][0] = (rv[d] && cL) ? L.y : 0.f;                          \
                W[d][1] = rv[d] ? M.x : 0.f;                                  \
                W[d][2] = rv[d] ? M.y : 0.f;                                  \
                W[d][3] = rv[d] ? M.z : 0.f;                                  \
                W[d][4] = rv[d] ? M.w : 0.f;                                  \
                W[d][5] = (rv[d] && cR) ? R.x : 0.f;                          \
            }                                                                 \
        }

    K1_LOAD(0, win[0]);
    #pragma unroll
    for (int c = 0; c < 4; ++c) {
        const int cur = c & 1;
        if (c < 3) K1_LOAD(c + 1, win[cur ^ 1]);
        #pragma unroll
        for (int g = 0; g < 4; ++g) {
            const float* wp = &w1[((cog * 4 + g) * 4 + c) * 9];
            #pragma unroll
            for (int d = 0; d < 3; ++d)
                #pragma unroll
                for (int j = 0; j < 3; ++j) {
                    float w = wp[3 * d + j];
                    acc[g][0] += w * win[cur][d][j];
                    acc[g][1] += w * win[cur][d][j + 1];
                    acc[g][2] += w * win[cur][d][j + 2];
                    acc[g][3] += w * win[cur][d][j + 3];
                }
        }
    }

    const int prow = 8 * rb + 2 * wv + (r >> 1);
    #pragma unroll
    for (int g = 0; g < 4; ++g) {
        float m0 = fmaxf(LRELU(acc[g][0]), LRELU(acc[g][1]));
        float m1 = fmaxf(LRELU(acc[g][2]), LRELU(acc[g][3]));
        float p0 = fmaxf(m0, __shfl_xor(m0, 16));   // all lanes execute
        float p1 = fmaxf(m1, __shfl_xor(m1, 16));
        if ((r & 1) == 0) {
            float* o = &P1H[((b * 32 + cog * 4 + g) * 34 + prow + 1) * 36 + 2 * q + 1];
            o[0] = 12.f * p0; o[1] = 12.f * p1;
        }
    }
}

// ---------- k2: conv2 32->64 @32x32, +4*b2, lrelu, pool2 -> p2H ------------
// block = (co-pair, row-half); waves split cin (8 each, SCALAR); LDS combine.
__global__ __launch_bounds__(256, 4) void k2(const float* __restrict__ P1H,
                                             const float* __restrict__ w2,
                                             const float* __restrict__ b2,
                                             float* __restrict__ p2H) {
    __shared__ float cbuf[3 * 64 * 20];   // 15 KB, stride-20 float4 = no conflicts
    const int bx  = blockIdx.x;           // 64 = cog(32) x rh(2)
    const int b   = blockIdx.y;
    const int cog = bx >> 1, rh = bx & 1;
    const int c0  = cog * 2;
    const int t   = threadIdx.x;
    const int l   = t & 63, wv = t >> 6;
    const int wvs = __builtin_amdgcn_readfirstlane(wv);   // scalar wave id
    const int R   = l >> 3, q = l & 7;
    const int r0  = 16 * rh + 2 * R;      // pre-pool rows r0, r0+1

    float acc[2][2][4];
    #pragma unroll
    for (int g = 0; g < 2; ++g) {
        float bias = (wvs == 0) ? 4.f * b2[c0 + g] : 0.f;
        #pragma unroll
        for (int orow = 0; orow < 2; ++orow) {
            acc[g][orow][0] = bias; acc[g][orow][1] = bias;
            acc[g][orow][2] = bias; acc[g][orow][3] = bias;
        }
    }

    float win[2][4][6];
    #define K2_LOAD(cin, W)                                                   \
        {                                                                     \
            const int plane = (b * 32 + (cin)) * 34;                          \
            _Pragma("unroll")                                                 \
            for (int d = 0; d < 4; ++d) {                                     \
                const float* pr = &P1H[(plane + r0 + d) * 36 + 4 * q];        \
                float4 M  = *(const float4*)pr;                               \
                float2 Rt = *(const float2*)(pr + 4);                         \
                W[d][0] = M.x; W[d][1] = M.y; W[d][2] = M.z;                  \
                W[d][3] = M.w; W[d][4] = Rt.x; W[d][5] = Rt.y;                \
            }                                                                 \
        }

    K2_LOAD(wvs * 8, win[0]);
    #pragma unroll
    for (int cl = 0; cl < 8; ++cl) {
        const int cur = cl & 1;
        if (cl < 7) K2_LOAD(wvs * 8 + cl + 1, win[cur ^ 1]);
        const int cin = wvs * 8 + cl;     // scalar -> weight reads are s_load
        #pragma unroll
        for (int g = 0; g < 2; ++g) {
            const float* wp = &w2[((c0 + g) * 32 + cin) * 9];
            #pragma unroll
            for (int d = 0; d < 3; ++d)
                #pragma unroll
                for (int j = 0; j < 3; ++j) {
                    float w = wp[3 * d + j];
                    #pragma unroll
                    for (int k = 0; k < 4; ++k) {
                        acc[g][0][k] += w * win[cur][d][j + k];
                        acc[g][1][k] += w * win[cur][d + 1][j + k];
                    }
                }
        }
    }

    if (wvs > 0) {
        float* cb = &cbuf[((wvs - 1) * 64 + l) * 20];
        #pragma unroll
        for (int g = 0; g < 2; ++g)
            #pragma unroll
            for (int orow = 0; orow < 2; ++orow)
                *(float4*)&cb[(g * 2 + orow) * 4] =
                    make_float4(acc[g][orow][0], acc[g][orow][1],
                                acc[g][orow][2], acc[g][orow][3]);
    }
    __syncthreads();

    if (wvs == 0) {
        #pragma unroll
        for (int k = 0; k < 3; ++k) {
            const float* cb = &cbuf[(k * 64 + l) * 20];
            #pragma unroll
            for (int g = 0; g < 2; ++g)
                #pragma unroll
                for (int orow = 0; orow < 2; ++orow) {
                    float4 v = *(const float4*)&cb[(g * 2 + orow) * 4];
                    acc[g][orow][0] += v.x; acc[g][orow][1] += v.y;
                    acc[g][orow][2] += v.z; acc[g][orow][3] += v.w;
                }
        }
        #pragma unroll
        for (int g = 0; g < 2; ++g) {
            float p0 = fmaxf(fmaxf(LRELU(acc[g][0][0]), LRELU(acc[g][0][1])),
                             fmaxf(LRELU(acc[g][1][0]), LRELU(acc[g][1][1])));
            float p1 = fmaxf(fmaxf(LRELU(acc[g][0][2]), LRELU(acc[g][0][3])),
                             fmaxf(LRELU(acc[g][1][2]), LRELU(acc[g][1][3])));
            float* o = &p2H[((b * 64 + c0 + g) * 18 + (8 * rh + R) + 1) * 20 + 2 * q + 1];
            o[0] = p0; o[1] = p1;
        }
    }
}

// ---------- k3: conv3 64->128 @16x16, +b3, lrelu, pool2, mean, dot ---------
// block = co-quad; waves split cin (16 each, SCALAR); LDS combine; reduction.
__global__ __launch_bounds__(256, 4) void k3(const float* __restrict__ p2H,
                                             const float* __restrict__ w3,
                                             const float* __restrict__ b3,
                                             const float* __restrict__ wc,
                                             const float* __restrict__ bc,
                                             float* __restrict__ out) {
    __shared__ float cbuf[3 * 64 * 20];   // 15 KB
    const int cog = blockIdx.x;           // 0..31 -> 4 co
    const int b   = blockIdx.y;
    const int t   = threadIdx.x;
    const int l   = t & 63, wv = t >> 6;
    const int wvs = __builtin_amdgcn_readfirstlane(wv);   // scalar wave id
    const int r   = l >> 2, q = l & 3;

    float acc[4][4];
    #pragma unroll
    for (int g = 0; g < 4; ++g) {
        float bias = (wvs == 0) ? b3[cog * 4 + g] : 0.f;
        acc[g][0] = bias; acc[g][1] = bias; acc[g][2] = bias; acc[g][3] = bias;
    }

    float win[2][3][6];
    #define K3_LOAD(cin, W)                                                   \
        {                                                                     \
            const int plane = (b * 64 + (cin)) * 18;                          \
            _Pragma("unroll")                                                 \
            for (int d = 0; d < 3; ++d) {                                     \
                const float* pr = &p2H[(plane + r + d) * 20 + 4 * q];         \
                float4 M  = *(const float4*)pr;                               \
                float2 Rt = *(const float2*)(pr + 4);                         \
                W[d][0] = M.x; W[d][1] = M.y; W[d][2] = M.z;                  \
                W[d][3] = M.w; W[d][4] = Rt.x; W[d][5] = Rt.y;                \
            }                                                                 \
        }

    K3_LOAD(wvs * 16, win[0]);
    #pragma unroll
    for (int cl = 0; cl < 16; ++cl) {
        const int cur = cl & 1;
        if (cl < 15) K3_LOAD(wvs * 16 + cl + 1, win[cur ^ 1]);
        const int cin = wvs * 16 + cl;    // scalar -> weight reads are s_load
        #pragma unroll
        for (int g = 0; g < 4; ++g) {
            const float* wp = &w3[((cog * 4 + g) * 64 + cin) * 9];
            #pragma unroll
            for (int d = 0; d < 3; ++d)
                #pragma unroll
                for (int j = 0; j < 3; ++j) {
                    float w = wp[3 * d + j];
                    acc[g][0] += w * win[cur][d][j];
                    acc[g][1] += w * win[cur][d][j + 1];
                    acc[g][2] += w * win[cur][d][j + 2];
                    acc[g][3] += w * win[cur][d][j + 3];
                }
        }
    }

    if (wvs > 0) {
        float* cb = &cbuf[((wvs - 1) * 64 + l) * 20];
        #pragma unroll
        for (int g = 0; g < 4; ++g)
            *(float4*)&cb[g * 4] =
                make_float4(acc[g][0], acc[g][1], acc[g][2], acc[g][3]);
    }
    __syncthreads();

    if (wvs == 0) {
        #pragma unroll
        for (int k = 0; k < 3; ++k) {
            const float* cb = &cbuf[(k * 64 + l) * 20];
            #pragma unroll
            for (int g = 0; g < 4; ++g) {
                float4 v = *(const float4*)&cb[g * 4];
                acc[g][0] += v.x; acc[g][1] += v.y;
                acc[g][2] += v.z; acc[g][3] += v.w;
            }
        }
        float vsum = 0.f;
        #pragma unroll
        for (int g = 0; g < 4; ++g) {
            float m0 = fmaxf(LRELU(acc[g][0]), LRELU(acc[g][1]));
            float m1 = fmaxf(LRELU(acc[g][2]), LRELU(acc[g][3]));
            float pm0 = fmaxf(m0, __shfl_xor(m0, 4));   // pool rows r, r+1
            float pm1 = fmaxf(m1, __shfl_xor(m1, 4));
            float contrib = ((r & 1) == 0) ? (pm0 + pm1) : 0.f;
            vsum += contrib * wc[cog * 4 + g];
        }
        #pragma unroll
        for (int off = 32; off > 0; off >>= 1) vsum += __shfl_xor(vsum, off);
        if (l == 0) {
            float o = vsum * (1.f / 64.f);
            if (cog == 0) o += bc[0];
            atomicAdd(&out[b], o);
        }
    }
}

extern "C" void kernel_launch(void* const* d_in, const int* in_sizes, int n_in,
                              void* d_out, int out_size, void* d_ws, size_t ws_size,
                              hipStream_t stream) {
    const float* x  = (const float*)d_in[0];
    const float* w1 = (const float*)d_in[1];
    const float* b1 = (const float*)d_in[2];
    const float* w2 = (const float*)d_in[3];
    const float* b2 = (const float*)d_in[4];
    const float* w3 = (const float*)d_in[5];
    const float* b3 = (const float*)d_in[6];
    const float* wc = (const float*)d_in[7];
    const float* bc = (const float*)d_in[8];
    float* out = (float*)d_out;

    float* P1H = (float*)d_ws;                    // [32][32][34][36] ~5.0 MB
    float* p2H = P1H + P1H_ELEMS;                 // [32][64][18][20] ~2.9 MB

    hipMemsetAsync(d_ws, 0, (size_t)(P1H_ELEMS + P2H_ELEMS) * sizeof(float), stream);
    hipMemsetAsync(out, 0, 32 * sizeof(float), stream);
    k1<<<dim3(32, 32), 256, 0, stream>>>(x, w1, b1, P1H);
    k2<<<dim3(64, 32), 256, 0, stream>>>(P1H, w2, b2, p2H);
    k3<<<dim3(32, 32), 256, 0, stream>>>(p2H, w3, b3, wc, bc, out);
}